// Round 8
// baseline (265.285 us; speedup 1.0000x reference)
//
#include <hip/hip_runtime.h>

// MultiHeadTEAttention MFMA version.
// M=8, NQ=NKV=1024, DX=512, H=8, HD=64, KHID=16, DT=2. f32 in/out, bf16 compute.
// R1: prep pass converts A->bf16, W->bf16 transposed.
// R2: gemm staged via global_load_lds (128x128 tile, BK=32).
// R6: gemm + XCD-grouping block swizzle.
// R7: attn bias hinge in packed f16 (pk_sub/pk_max/dot2). 56 VGPR.
// R8: pk2 via hardware v_cvt_pk_bf16_f32 (1 instr per 2 elems vs ~6 manual RNE
//     -- prep was ~60us of conversion VALU); attn adds exact defer-rescale
//     (skip alpha/o-rescale when no lane saw a new max).

typedef unsigned short u16;
typedef unsigned int   u32;
typedef short bf8 __attribute__((ext_vector_type(8)));   // 8 bf16 = 4 VGPR
typedef float f4  __attribute__((ext_vector_type(4)));
typedef _Float16 h2 __attribute__((ext_vector_type(2))); // packed half2

#define Mb 8
#define SCALE 0.125f
#define NTOK 4194304   // Mb*1024*512

__device__ __forceinline__ u16 f2bf(float f) {
    union { float f; u32 u; } v; v.f = f;
    u32 r = v.u + 0x7fffu + ((v.u >> 16) & 1u);   // RNE
    return (u16)(r >> 16);
}
// hardware packed f32->bf16 (RNE, bit-identical to manual RNE)
__device__ __forceinline__ u32 pk2(float a, float b) {
    u32 r;
    asm("v_cvt_pk_bf16_f32 %0, %1, %2" : "=v"(r) : "v"(a), "v"(b));
    return r;
}
__device__ __forceinline__ void gl_lds16(const u16* g, u16* l) {
    __builtin_amdgcn_global_load_lds(
        (const __attribute__((address_space(1))) u32*)g,
        (__attribute__((address_space(3))) u32*)l, 16, 0, 0);
}
__device__ __forceinline__ h2 h2_of(u32 x) {
    union { u32 u; h2 h; } c; c.u = x; return c.h;
}
__device__ __forceinline__ u32 u_of(h2 x) {
    union { h2 h; u32 u; } c; c.h = x; return c.u;
}
__device__ __forceinline__ float dot2(h2 a, h2 b, float c) {
#if __has_builtin(__builtin_amdgcn_fdot2)
    return __builtin_amdgcn_fdot2(a, b, c, false);
#else
    return fmaf((float)a[0], (float)b[0], fmaf((float)a[1], (float)b[1], c));
#endif
}

// ===========================================================================
// prep: one-time conversions.
//   blocks [0,1536):  xq|xk|xv f32 -> bf16 (3*NTOK elems)
//   blocks [1536,1792): w_q|w_k|w_v|w_out 512x512 f32 -> bf16 TRANSPOSED
//                       dstW[mat][n][k] = w[mat][k][n]
// ===========================================================================
struct PArgs {
    const float* xs[3];
    const float* ws[4];
    u16* dstA;
    u16* dstW;
};

__global__ __launch_bounds__(256) void prep(PArgs p) {
    __shared__ u16 tl[64][80];   // [n within tile][k within tile], padded
    const int tid = threadIdx.x;
    const int b = blockIdx.x;
    if (b < 1536) {
        #pragma unroll
        for (int it = 0; it < 4; ++it) {
            const u32 u = (u32)b * 256u + (u32)tid + (u32)it * 393216u;  // 8-elem unit
            const int arr = u >> 19;                    // NTOK/8 = 524288 units/array
            const size_t off = (size_t)(u & 524287u) * 8;
            const float* s = p.xs[arr];
            float4 a0 = *(const float4*)(s + off);
            float4 a1 = *(const float4*)(s + off + 4);
            uint4 v;
            v.x = pk2(a0.x, a0.y); v.y = pk2(a0.z, a0.w);
            v.z = pk2(a1.x, a1.y); v.w = pk2(a1.z, a1.w);
            *(uint4*)(p.dstA + (size_t)arr * NTOK + off) = v;
        }
    } else {
        const int bb = b - 1536;
        const int mat = bb >> 6, t = bb & 63;
        const int kt = t >> 3, nt = t & 7;              // 64x64 tile coords
        const float* src = p.ws[mat] + (size_t)kt * 64 * 512 + (size_t)nt * 64;
        const int r0 = tid >> 4, c4 = (tid & 15) * 4;
        #pragma unroll
        for (int rr = 0; rr < 4; ++rr) {
            const int row = r0 + rr * 16;               // k within tile
            float4 a = *(const float4*)(src + (size_t)row * 512 + c4);
            tl[c4 + 0][row] = f2bf(a.x);
            tl[c4 + 1][row] = f2bf(a.y);
            tl[c4 + 2][row] = f2bf(a.z);
            tl[c4 + 3][row] = f2bf(a.w);
        }
        __syncthreads();
        u16* dst = p.dstW + (size_t)mat * 262144 + (size_t)nt * 64 * 512 + (size_t)kt * 64;
        #pragma unroll
        for (int i = 0; i < 2; ++i) {
            const int s2 = tid + i * 256;
            const int nrow = s2 >> 3, k8 = (s2 & 7) * 8;
            *(uint4*)(dst + (size_t)nrow * 512 + k8) = *(const uint4*)&tl[nrow][k8];
        }
    }
}

// ===========================================================================
// GEMM: C = A[8192x512] @ W[512x512] (+bias). bf16 MFMA, f32 accumulate.
// A bf16 row-major; W bf16 pre-transposed [n][k]. Tile 128x128, BK=32.
// LDS linear [row][32k], staged via global_load_lds, source octet XOR-swizzled,
// reads de-swizzled. XCD-grouping block swizzle (R6).
// ===========================================================================
struct GArgs {
    const u16*   A[3];
    const u16*   W[3];      // transposed [n][512] bf16
    void*        C[3];
    const float* bias;
    int          modeT[3];
    int          outf32;
};

__global__ __launch_bounds__(256) void gemm_mfma(GArgs g) {
    __shared__ u16 Xs[128][32];
    __shared__ u16 Ws[128][32];

    const int z   = blockIdx.z;
    const int tid = threadIdx.x;
    const int w = tid >> 6, lane = tid & 63, quad = lane >> 4, l16 = lane & 15;
    const int wm = w >> 1, wn = w & 1;
    const int bid = blockIdx.y * 4 + blockIdx.x;
    const int swz = ((bid & 7) << 5) | (bid >> 3);
    const int n0 = (swz & 3) * 128, t0 = (swz >> 2) * 128;
    const int trans = g.modeT[z];

    f4 acc[4][4];
    #pragma unroll
    for (int i = 0; i < 4; ++i)
        #pragma unroll
        for (int j = 0; j < 4; ++j) acc[i][j] = (f4)0.f;

    const int lrow  = lane >> 2;                       // 0..15
    const int kslot = (lane & 3) ^ ((lane >> 3) & 3);  // swizzled k-octet
    u16* ldsX0 = &Xs[w * 32][0];
    u16* ldsX1 = &Xs[w * 32 + 16][0];
    u16* ldsW0 = &Ws[w * 32][0];
    u16* ldsW1 = &Ws[w * 32 + 16][0];
    const u16* gA0 = g.A[z] + (size_t)(t0 + w * 32 + lrow) * 512 + kslot * 8;
    const u16* gA1 = gA0 + 16 * 512;
    const u16* gW0 = g.W[z] + (size_t)(n0 + w * 32 + lrow) * 512 + kslot * 8;
    const u16* gW1 = gW0 + 16 * 512;

    const int rslot = (quad ^ ((l16 >> 1) & 3)) * 8;

    for (int kc = 0; kc < 512; kc += 32) {
        __syncthreads();
        gl_lds16(gA0 + kc, ldsX0);
        gl_lds16(gA1 + kc, ldsX1);
        gl_lds16(gW0 + kc, ldsW0);
        gl_lds16(gW1 + kc, ldsW1);
        __syncthreads();

        const u16* Abase = trans ? &Xs[0][0] : &Ws[0][0];
        const u16* Bbase = trans ? &Ws[0][0] : &Xs[0][0];
        const int arow = (trans ? wm : wn) * 64;
        const int brow = (trans ? wn : wm) * 64;
        bf8 af[4], bf[4];
        #pragma unroll
        for (int i = 0; i < 4; ++i)
            af[i] = *(const bf8*)(Abase + (arow + i * 16 + l16) * 32 + rslot);
        #pragma unroll
        for (int j = 0; j < 4; ++j)
            bf[j] = *(const bf8*)(Bbase + (brow + j * 16 + l16) * 32 + rslot);
        #pragma unroll
        for (int i = 0; i < 4; ++i)
            #pragma unroll
            for (int j = 0; j < 4; ++j)
                acc[i][j] = __builtin_amdgcn_mfma_f32_16x16x32_bf16(af[i], bf[j], acc[i][j], 0, 0, 0);
    }

    // ---- epilogue ----
    if (g.outf32) {
        float* Co = (float*)g.C[z];
        #pragma unroll
        for (int i = 0; i < 4; ++i) {
            const int nb = n0 + wn * 64 + i * 16 + quad * 4;
            float4 bv = *(const float4*)&g.bias[nb];
            #pragma unroll
            for (int j = 0; j < 4; ++j) {
                const int tok = t0 + wm * 64 + j * 16 + l16;
                float4 st;
                st.x = acc[i][j][0] + bv.x; st.y = acc[i][j][1] + bv.y;
                st.z = acc[i][j][2] + bv.z; st.w = acc[i][j][3] + bv.w;
                *(float4*)&Co[(size_t)tok * 512 + nb] = st;
            }
        }
    } else if (!trans) {
        u16* C = (u16*)g.C[z];
        #pragma unroll
        for (int i = 0; i < 4; ++i) {
            const int nb = n0 + wn * 64 + i * 16 + quad * 4;
            #pragma unroll
            for (int j = 0; j < 4; ++j) {
                const int tok = t0 + wm * 64 + j * 16 + l16;
                uint2 pw;
                pw.x = pk2(acc[i][j][0], acc[i][j][1]);
                pw.y = pk2(acc[i][j][2], acc[i][j][3]);
                *(uint2*)&C[(size_t)tok * 512 + nb] = pw;
            }
        }
    } else {
        u16* Vt = (u16*)g.C[z];
        #pragma unroll
        for (int i = 0; i < 4; ++i) {
            const int tokb = t0 + wm * 64 + i * 16 + quad * 4;
            const int mb = tokb >> 10, tb = tokb & 1023;
            #pragma unroll
            for (int j = 0; j < 4; ++j) {
                const int n = n0 + wn * 64 + j * 16 + l16;
                uint2 pw;
                pw.x = pk2(acc[i][j][0], acc[i][j][1]);
                pw.y = pk2(acc[i][j][2], acc[i][j][3]);
                *(uint2*)&Vt[(size_t)mb * 524288 + (size_t)n * 1024 + tb] = pw;
            }
        }
    }
}

// ===========================================================================
// Fused flash attention (MFMA). Block = (qt, h, m): 64 queries, one head.
// S^T = K·Q^T, online softmax per q-col, O^T = Vt·P^T.  (R7 structure.)
// R8: exact defer-rescale -- when no lane of the wave observed a new max
//     (mnew == mrun for every lane), skip alpha exp / O-rescale / mrun update.
// ===========================================================================
__global__ __launch_bounds__(256) void attn_mfma(
    const u16* __restrict__ Q, const u16* __restrict__ K,
    const u16* __restrict__ Vt,
    const float* __restrict__ tqp, const float* __restrict__ tkp,
    const float* __restrict__ kw1, const float* __restrict__ kb1,
    const float* __restrict__ kw2,
    u16* __restrict__ O)
{
    __shared__ u16   sK[8][64][8];    // [d-octet][key][8 bf16]
    __shared__ u16   sV[8][64][8];    // [key-octet][d][8 bf16]
    __shared__ u32   sv2[8][68];      // [c-pair][key] : half2(v[2cp][k], v[2cp+1][k])
    __shared__ u16   sP[4][16][68];   // per-wave P [q][key], +4 pad

    const int tid = threadIdx.x;
    const int w = tid >> 6, lane = tid & 63, quad = lane >> 4, l16 = lane & 15;
    const int qt = blockIdx.x, h = blockIdx.y, m = blockIdx.z;
    const int q0 = qt * 64;
    const size_t qtok = (size_t)m * 1024 + q0 + w * 16 + l16;

    // Q fragments (d = kc*32 + quad*8 + j), q = l16
    bf8 qf[2];
    {
        const u16* qp = Q + qtok * 512 + h * 64 + quad * 8;
        qf[0] = *(const bf8*)qp;
        qf[1] = *(const bf8*)(qp + 32);
    }
    // u_q[c] = tq@kw1 + kb1 ; w2h[c] = kw2[c][h]  (kb2 softmax-invariant)
    // packed: u2[cp] = (u[2cp], u[2cp+1]) f16 ; w2p[cp] likewise
    h2 u2[8], w2p[8];
    {
        const float t0v = tqp[qtok * 2], t1v = tqp[qtok * 2 + 1];
        #pragma unroll
        for (int cp = 0; cp < 8; ++cp) {
            const int c0 = 2 * cp, c1 = 2 * cp + 1;
            float ua = fmaf(t0v, kw1[c0], fmaf(t1v, kw1[16 + c0], kb1[c0]));
            float ub = fmaf(t0v, kw1[c1], fmaf(t1v, kw1[16 + c1], kb1[c1]));
            u2[cp][0]  = (_Float16)ua;            u2[cp][1]  = (_Float16)ub;
            w2p[cp][0] = (_Float16)kw2[c0 * 8 + h]; w2p[cp][1] = (_Float16)kw2[c1 * 8 + h];
        }
    }

    float mrun = -1e30f, lrun = 0.f;
    f4 o[4];
    #pragma unroll
    for (int d = 0; d < 4; ++d) o[d] = (f4)0.f;

    for (int kt = 0; kt < 16; ++kt) {
        const int k0 = kt * 64;
        __syncthreads();
        // ---- stage K tile: sK[seg][key] = K[k0+key][h*64 + seg*8 ..] ----
        #pragma unroll
        for (int i = 0; i < 2; ++i) {
            const int s = tid + i * 256;
            const int seg = s >> 6, key = s & 63;
            const u16* kp = K + ((size_t)m * 1024 + k0 + key) * 512 + h * 64 + seg * 8;
            *(uint4*)&sK[seg][key][0] = *(const uint4*)kp;
        }
        // ---- stage V tile: sV[ks][d] = Vt[h*64+d][k0 + ks*8 ..] ----
        #pragma unroll
        for (int i = 0; i < 2; ++i) {
            const int s = tid + i * 256;
            const int ks = s >> 6, d = s & 63;
            const u16* vp = Vt + (size_t)m * 524288 + (size_t)(h * 64 + d) * 1024 + k0 + ks * 8;
            *(uint4*)&sV[ks][d][0] = *(const uint4*)vp;
        }
        // ---- stage sv2[cp][k] = half2(tk[k]@kw1[:,2cp], tk[k]@kw1[:,2cp+1]) ----
        {
            const int cp = tid >> 5;            // 0..7
            const int k2 = (tid & 31) * 2;      // even key
            const float* tkq = tkp + ((size_t)m * 1024 + k0 + k2) * 2;
            float4 t = *(const float4*)tkq;     // tk[k2], tk[k2+1]
            const float w0a = kw1[2 * cp],     w1a = kw1[16 + 2 * cp];
            const float w0b = kw1[2 * cp + 1], w1b = kw1[16 + 2 * cp + 1];
            h2 p0, p1;
            p0[0] = (_Float16)fmaf(t.x, w0a, t.y * w1a);
            p0[1] = (_Float16)fmaf(t.x, w0b, t.y * w1b);
            p1[0] = (_Float16)fmaf(t.z, w0a, t.w * w1a);
            p1[1] = (_Float16)fmaf(t.z, w0b, t.w * w1b);
            uint2 pw; pw.x = u_of(p0); pw.y = u_of(p1);
            *(uint2*)&sv2[cp][k2] = pw;
        }
        __syncthreads();

        // ---- S^T = K·Q^T : s[msub] rows = keys msub*16+quad*4+r, col q=l16 ----
        f4 s[4];
        #pragma unroll
        for (int msub = 0; msub < 4; ++msub) {
            bf8 kf0 = *(const bf8*)&sK[quad][msub * 16 + l16][0];
            bf8 kf1 = *(const bf8*)&sK[4 + quad][msub * 16 + l16][0];
            s[msub] = __builtin_amdgcn_mfma_f32_16x16x32_bf16(kf0, qf[0], (f4)0.f, 0, 0, 0);
            s[msub] = __builtin_amdgcn_mfma_f32_16x16x32_bf16(kf1, qf[1], s[msub], 0, 0, 0);
        }
        // ---- bias: s = s*SCALE + sum_c relu(u[c]-v[c,k])*w2h[c]  (packed f16) ----
        #pragma unroll
        for (int msub = 0; msub < 4; ++msub) {
            const int kb = msub * 16 + quad * 4;
            f4 b = (f4)0.f;
            #pragma unroll
            for (int cp = 0; cp < 8; ++cp) {
                uint4 vv = *(const uint4*)&sv2[cp][kb];
                const h2 uc = u2[cp], wc = w2p[cp];
                const h2 z = (h2)(_Float16)0.f;
                h2 d0 = uc - h2_of(vv.x);
                h2 d1 = uc - h2_of(vv.y);
                h2 d2 = uc - h2_of(vv.z);
                h2 d3 = uc - h2_of(vv.w);
                d0 = __builtin_elementwise_max(d0, z);
                d1 = __builtin_elementwise_max(d1, z);
                d2 = __builtin_elementwise_max(d2, z);
                d3 = __builtin_elementwise_max(d3, z);
                b[0] = dot2(d0, wc, b[0]);
                b[1] = dot2(d1, wc, b[1]);
                b[2] = dot2(d2, wc, b[2]);
                b[3] = dot2(d3, wc, b[3]);
            }
            s[msub] = s[msub] * SCALE + b;
        }
        // ---- online softmax over keys (rows spread over quads) ----
        float mx = -1e30f;
        #pragma unroll
        for (int msub = 0; msub < 4; ++msub) {
            mx = fmaxf(mx, fmaxf(fmaxf(s[msub][0], s[msub][1]),
                                 fmaxf(s[msub][2], s[msub][3])));
        }
        mx = fmaxf(mx, __shfl_xor(mx, 16));
        mx = fmaxf(mx, __shfl_xor(mx, 32));
        const float mnew = fmaxf(mrun, mx);
        float ps = 0.f;
        #pragma unroll
        for (int msub = 0; msub < 4; ++msub) {
            #pragma unroll
            for (int r = 0; r < 4; ++r) {
                float p = __expf(s[msub][r] - mnew);
                s[msub][r] = p;
                ps += p;
            }
        }
        ps += __shfl_xor(ps, 16);
        ps += __shfl_xor(ps, 32);
        if (__all(mx <= mrun)) {
            // no lane saw a new max: mnew == mrun, alpha == 1 exactly
            lrun += ps;
        } else {
            const float alpha = __expf(mrun - mnew);
            lrun = lrun * alpha + ps;
            mrun = mnew;
            #pragma unroll
            for (int d = 0; d < 4; ++d) o[d] = o[d] * alpha;
        }
        // ---- write P (bf16) to wave-private sP[q][key] ----
        #pragma unroll
        for (int msub = 0; msub < 4; ++msub) {
            uint2 pw;
            pw.x = pk2(s[msub][0], s[msub][1]);
            pw.y = pk2(s[msub][2], s[msub][3]);
            *(uint2*)&sP[w][l16][msub * 16 + quad * 4] = pw;
        }
        // ---- O^T += Vt·P^T ----
        #pragma unroll
        for (int dsub = 0; dsub < 4; ++dsub) {
            #pragma unroll
            for (int kc2 = 0; kc2 < 2; ++kc2) {
                bf8 vf = *(const bf8*)&sV[kc2 * 4 + quad][dsub * 16 + l16][0];
                bf8 pf = *(const bf8*)&sP[w][l16][kc2 * 32 + quad * 8];
                o[dsub] = __builtin_amdgcn_mfma_f32_16x16x32_bf16(vf, pf, o[dsub], 0, 0, 0);
            }
        }
    }

    // ---- epilogue: O[tok][h*64 + d] = o/l ----
    const float inv = 1.f / lrun;
    #pragma unroll
    for (int dsub = 0; dsub < 4; ++dsub) {
        uint2 pw;
        pw.x = pk2(o[dsub][0] * inv, o[dsub][1] * inv);
        pw.y = pk2(o[dsub][2] * inv, o[dsub][3] * inv);
        *(uint2*)&O[qtok * 512 + h * 64 + dsub * 16 + quad * 4] = pw;
    }
}

// ===========================================================================
extern "C" void kernel_launch(void* const* d_in, const int* in_sizes, int n_in,
                              void* d_out, int out_size, void* d_ws, size_t ws_size,
                              hipStream_t stream) {
    const float* xq    = (const float*)d_in[0];
    const float* xk    = (const float*)d_in[1];
    const float* xv    = (const float*)d_in[2];
    const float* tq    = (const float*)d_in[3];
    const float* tk    = (const float*)d_in[4];
    const float* w_q   = (const float*)d_in[5];
    const float* w_k   = (const float*)d_in[6];
    const float* w_v   = (const float*)d_in[7];
    const float* w_out = (const float*)d_in[8];
    const float* b_out = (const float*)d_in[9];
    const float* kw1   = (const float*)d_in[10];
    const float* kb1   = (const float*)d_in[11];
    const float* kw2   = (const float*)d_in[12];

    // workspace: Q | K | Vt | Aq | Ak | Av | Wq | Wk | Wv | Wo   (50 MiB)
    u16* Q  = (u16*)d_ws;
    u16* Kp = Q  + NTOK;
    u16* Vt = Kp + NTOK;
    u16* Aq = Vt + NTOK;
    u16* Ak = Aq + NTOK;
    u16* Av = Ak + NTOK;
    u16* Wq = Av + NTOK;
    u16* Wk = Wq + 262144;
    u16* Wv = Wk + 262144;
    u16* Wo = Wv + 262144;
    u16* O  = Aq;            // Aq is dead after gemm1; reuse for attn output

    // --- one-time conversions (A's -> bf16, W's -> bf16 transposed) ---
    PArgs p;
    p.xs[0] = xq;  p.xs[1] = xk;  p.xs[2] = xv;
    p.ws[0] = w_q; p.ws[1] = w_k; p.ws[2] = w_v; p.ws[3] = w_out;
    p.dstA = Aq;   p.dstW = Wq;
    prep<<<dim3(1792), 256, 0, stream>>>(p);

    // --- QKV projections (V stored transposed per batch) ---
    GArgs gq;
    gq.A[0] = Aq;  gq.A[1] = Ak;  gq.A[2] = Av;
    gq.W[0] = Wq;  gq.W[1] = Wk;  gq.W[2] = Wv;
    gq.C[0] = Q;   gq.C[1] = Kp;  gq.C[2] = Vt;
    gq.bias = nullptr;
    gq.modeT[0] = 0; gq.modeT[1] = 0; gq.modeT[2] = 1;
    gq.outf32 = 0;
    gemm_mfma<<<dim3(4, 64, 3), 256, 0, stream>>>(gq);

    // --- fused attention ---
    attn_mfma<<<dim3(16, 8, Mb), 256, 0, stream>>>(Q, Kp, Vt, tq, tk,
                                                   kw1, kb1, kw2, O);

    // --- output projection (f32 + bias) ---
    GArgs go;
    go.A[0] = O;   go.A[1] = O;   go.A[2] = O;
    go.W[0] = Wo;  go.W[1] = Wo;  go.W[2] = Wo;
    go.C[0] = d_out; go.C[1] = d_out; go.C[2] = d_out;
    go.bias = b_out;
    go.modeT[0] = 0; go.modeT[1] = 0; go.modeT[2] = 0;
    go.outf32 = 1;
    gemm_mfma<<<dim3(4, 64, 1), 256, 0, stream>>>(go);
}

// Round 9
// 246.863 us; speedup vs baseline: 1.0746x; 1.0746x over previous
//
#include <hip/hip_runtime.h>

// MultiHeadTEAttention MFMA version.
// M=8, NQ=NKV=1024, DX=512, H=8, HD=64, KHID=16, DT=2. f32 in/out, bf16 compute.
// R1: prep pass converts A->bf16, W->bf16 transposed.
// R2/R6: gemm via global_load_lds, 128x128 tile, XCD-grouping swizzle.
// R7: attn bias hinge in packed f16. R8: hw v_cvt_pk_bf16_f32; defer-rescale.
// R9: attn restructured: 512-thread blocks (128 q), K/V staged via
//     global_load_lds (wave-linear dest), double-buffered with prefetch
//     issued before compute and ONE __syncthreads per tile.

typedef unsigned short u16;
typedef unsigned int   u32;
typedef short bf8 __attribute__((ext_vector_type(8)));   // 8 bf16 = 4 VGPR
typedef float f4  __attribute__((ext_vector_type(4)));
typedef _Float16 h2 __attribute__((ext_vector_type(2))); // packed half2

#define Mb 8
#define SCALE 0.125f
#define NTOK 4194304   // Mb*1024*512

__device__ __forceinline__ u16 f2bf(float f) {
    union { float f; u32 u; } v; v.f = f;
    u32 r = v.u + 0x7fffu + ((v.u >> 16) & 1u);   // RNE
    return (u16)(r >> 16);
}
// hardware packed f32->bf16 (RNE, bit-identical to manual RNE)
__device__ __forceinline__ u32 pk2(float a, float b) {
    u32 r;
    asm("v_cvt_pk_bf16_f32 %0, %1, %2" : "=v"(r) : "v"(a), "v"(b));
    return r;
}
__device__ __forceinline__ void gl_lds16(const u16* g, u16* l) {
    __builtin_amdgcn_global_load_lds(
        (const __attribute__((address_space(1))) u32*)g,
        (__attribute__((address_space(3))) u32*)l, 16, 0, 0);
}
__device__ __forceinline__ h2 h2_of(u32 x) {
    union { u32 u; h2 h; } c; c.u = x; return c.h;
}
__device__ __forceinline__ u32 u_of(h2 x) {
    union { h2 h; u32 u; } c; c.h = x; return c.u;
}
__device__ __forceinline__ float dot2(h2 a, h2 b, float c) {
#if __has_builtin(__builtin_amdgcn_fdot2)
    return __builtin_amdgcn_fdot2(a, b, c, false);
#else
    return fmaf((float)a[0], (float)b[0], fmaf((float)a[1], (float)b[1], c));
#endif
}

// ===========================================================================
// prep: one-time conversions. (R8 version, unchanged)
// ===========================================================================
struct PArgs {
    const float* xs[3];
    const float* ws[4];
    u16* dstA;
    u16* dstW;
};

__global__ __launch_bounds__(256) void prep(PArgs p) {
    __shared__ u16 tl[64][80];   // [n within tile][k within tile], padded
    const int tid = threadIdx.x;
    const int b = blockIdx.x;
    if (b < 1536) {
        #pragma unroll
        for (int it = 0; it < 4; ++it) {
            const u32 u = (u32)b * 256u + (u32)tid + (u32)it * 393216u;  // 8-elem unit
            const int arr = u >> 19;                    // NTOK/8 = 524288 units/array
            const size_t off = (size_t)(u & 524287u) * 8;
            const float* s = p.xs[arr];
            float4 a0 = *(const float4*)(s + off);
            float4 a1 = *(const float4*)(s + off + 4);
            uint4 v;
            v.x = pk2(a0.x, a0.y); v.y = pk2(a0.z, a0.w);
            v.z = pk2(a1.x, a1.y); v.w = pk2(a1.z, a1.w);
            *(uint4*)(p.dstA + (size_t)arr * NTOK + off) = v;
        }
    } else {
        const int bb = b - 1536;
        const int mat = bb >> 6, t = bb & 63;
        const int kt = t >> 3, nt = t & 7;              // 64x64 tile coords
        const float* src = p.ws[mat] + (size_t)kt * 64 * 512 + (size_t)nt * 64;
        const int r0 = tid >> 4, c4 = (tid & 15) * 4;
        #pragma unroll
        for (int rr = 0; rr < 4; ++rr) {
            const int row = r0 + rr * 16;               // k within tile
            float4 a = *(const float4*)(src + (size_t)row * 512 + c4);
            tl[c4 + 0][row] = f2bf(a.x);
            tl[c4 + 1][row] = f2bf(a.y);
            tl[c4 + 2][row] = f2bf(a.z);
            tl[c4 + 3][row] = f2bf(a.w);
        }
        __syncthreads();
        u16* dst = p.dstW + (size_t)mat * 262144 + (size_t)nt * 64 * 512 + (size_t)kt * 64;
        #pragma unroll
        for (int i = 0; i < 2; ++i) {
            const int s2 = tid + i * 256;
            const int nrow = s2 >> 3, k8 = (s2 & 7) * 8;
            *(uint4*)(dst + (size_t)nrow * 512 + k8) = *(const uint4*)&tl[nrow][k8];
        }
    }
}

// ===========================================================================
// GEMM (R6/R8 version, unchanged): 128x128, BK=32, gl_lds, XCD-group swizzle.
// ===========================================================================
struct GArgs {
    const u16*   A[3];
    const u16*   W[3];      // transposed [n][512] bf16
    void*        C[3];
    const float* bias;
    int          modeT[3];
    int          outf32;
};

__global__ __launch_bounds__(256) void gemm_mfma(GArgs g) {
    __shared__ u16 Xs[128][32];
    __shared__ u16 Ws[128][32];

    const int z   = blockIdx.z;
    const int tid = threadIdx.x;
    const int w = tid >> 6, lane = tid & 63, quad = lane >> 4, l16 = lane & 15;
    const int wm = w >> 1, wn = w & 1;
    const int bid = blockIdx.y * 4 + blockIdx.x;
    const int swz = ((bid & 7) << 5) | (bid >> 3);
    const int n0 = (swz & 3) * 128, t0 = (swz >> 2) * 128;
    const int trans = g.modeT[z];

    f4 acc[4][4];
    #pragma unroll
    for (int i = 0; i < 4; ++i)
        #pragma unroll
        for (int j = 0; j < 4; ++j) acc[i][j] = (f4)0.f;

    const int lrow  = lane >> 2;                       // 0..15
    const int kslot = (lane & 3) ^ ((lane >> 3) & 3);  // swizzled k-octet
    u16* ldsX0 = &Xs[w * 32][0];
    u16* ldsX1 = &Xs[w * 32 + 16][0];
    u16* ldsW0 = &Ws[w * 32][0];
    u16* ldsW1 = &Ws[w * 32 + 16][0];
    const u16* gA0 = g.A[z] + (size_t)(t0 + w * 32 + lrow) * 512 + kslot * 8;
    const u16* gA1 = gA0 + 16 * 512;
    const u16* gW0 = g.W[z] + (size_t)(n0 + w * 32 + lrow) * 512 + kslot * 8;
    const u16* gW1 = gW0 + 16 * 512;

    const int rslot = (quad ^ ((l16 >> 1) & 3)) * 8;

    for (int kc = 0; kc < 512; kc += 32) {
        __syncthreads();
        gl_lds16(gA0 + kc, ldsX0);
        gl_lds16(gA1 + kc, ldsX1);
        gl_lds16(gW0 + kc, ldsW0);
        gl_lds16(gW1 + kc, ldsW1);
        __syncthreads();

        const u16* Abase = trans ? &Xs[0][0] : &Ws[0][0];
        const u16* Bbase = trans ? &Ws[0][0] : &Xs[0][0];
        const int arow = (trans ? wm : wn) * 64;
        const int brow = (trans ? wn : wm) * 64;
        bf8 af[4], bf[4];
        #pragma unroll
        for (int i = 0; i < 4; ++i)
            af[i] = *(const bf8*)(Abase + (arow + i * 16 + l16) * 32 + rslot);
        #pragma unroll
        for (int j = 0; j < 4; ++j)
            bf[j] = *(const bf8*)(Bbase + (brow + j * 16 + l16) * 32 + rslot);
        #pragma unroll
        for (int i = 0; i < 4; ++i)
            #pragma unroll
            for (int j = 0; j < 4; ++j)
                acc[i][j] = __builtin_amdgcn_mfma_f32_16x16x32_bf16(af[i], bf[j], acc[i][j], 0, 0, 0);
    }

    // ---- epilogue ----
    if (g.outf32) {
        float* Co = (float*)g.C[z];
        #pragma unroll
        for (int i = 0; i < 4; ++i) {
            const int nb = n0 + wn * 64 + i * 16 + quad * 4;
            float4 bv = *(const float4*)&g.bias[nb];
            #pragma unroll
            for (int j = 0; j < 4; ++j) {
                const int tok = t0 + wm * 64 + j * 16 + l16;
                float4 st;
                st.x = acc[i][j][0] + bv.x; st.y = acc[i][j][1] + bv.y;
                st.z = acc[i][j][2] + bv.z; st.w = acc[i][j][3] + bv.w;
                *(float4*)&Co[(size_t)tok * 512 + nb] = st;
            }
        }
    } else if (!trans) {
        u16* C = (u16*)g.C[z];
        #pragma unroll
        for (int i = 0; i < 4; ++i) {
            const int nb = n0 + wn * 64 + i * 16 + quad * 4;
            #pragma unroll
            for (int j = 0; j < 4; ++j) {
                const int tok = t0 + wm * 64 + j * 16 + l16;
                uint2 pw;
                pw.x = pk2(acc[i][j][0], acc[i][j][1]);
                pw.y = pk2(acc[i][j][2], acc[i][j][3]);
                *(uint2*)&C[(size_t)tok * 512 + nb] = pw;
            }
        }
    } else {
        u16* Vt = (u16*)g.C[z];
        #pragma unroll
        for (int i = 0; i < 4; ++i) {
            const int tokb = t0 + wm * 64 + i * 16 + quad * 4;
            const int mb = tokb >> 10, tb = tokb & 1023;
            #pragma unroll
            for (int j = 0; j < 4; ++j) {
                const int n = n0 + wn * 64 + j * 16 + l16;
                uint2 pw;
                pw.x = pk2(acc[i][j][0], acc[i][j][1]);
                pw.y = pk2(acc[i][j][2], acc[i][j][3]);
                *(uint2*)&Vt[(size_t)mb * 524288 + (size_t)n * 1024 + tb] = pw;
            }
        }
    }
}

// ===========================================================================
// Fused flash attention (MFMA). R9: block = (qt, h, m) with 128 queries,
// 8 waves; wave w owns queries q0+w*16..+15. K/V/sv2 double-buffered:
// per tile, prefetch of tile kt+1 (gl_lds K/V + sv2 ds_write) is issued
// BEFORE compute of tile kt; single __syncthreads at iteration end drains.
// Wave w stages K d-octet w and V key-octet w via global_load_lds
// (wave-uniform LDS base + lane*16B).
// ===========================================================================
__global__ __launch_bounds__(512) void attn_mfma(
    const u16* __restrict__ Q, const u16* __restrict__ K,
    const u16* __restrict__ Vt,
    const float* __restrict__ tqp, const float* __restrict__ tkp,
    const float* __restrict__ kw1, const float* __restrict__ kb1,
    const float* __restrict__ kw2,
    u16* __restrict__ O)
{
    __shared__ u16 sK[2][8][64][8];   // [buf][d-octet][key][8 bf16]
    __shared__ u16 sV[2][8][64][8];   // [buf][key-octet][d][8 bf16]
    __shared__ u32 sv2[2][8][68];     // [buf][c-pair][key] half2
    __shared__ u16 sP[8][16][68];     // per-wave P [q][key], +4 pad

    const int tid = threadIdx.x;
    const int w = tid >> 6, lane = tid & 63, quad = lane >> 4, l16 = lane & 15;
    const int qt = blockIdx.x, h = blockIdx.y, m = blockIdx.z;
    const int q0 = qt * 128;
    const size_t qtok = (size_t)m * 1024 + q0 + w * 16 + l16;

    // Q fragments (d = kc*32 + quad*8 + j), q = l16
    bf8 qf[2];
    {
        const u16* qp = Q + qtok * 512 + h * 64 + quad * 8;
        qf[0] = *(const bf8*)qp;
        qf[1] = *(const bf8*)(qp + 32);
    }
    // u2[cp] = f16x2 of (tq@kw1+kb1); w2p[cp] = f16x2 of kw2[:,h]
    h2 u2[8], w2p[8];
    {
        const float t0v = tqp[qtok * 2], t1v = tqp[qtok * 2 + 1];
        #pragma unroll
        for (int cp = 0; cp < 8; ++cp) {
            const int c0 = 2 * cp, c1 = 2 * cp + 1;
            float ua = fmaf(t0v, kw1[c0], fmaf(t1v, kw1[16 + c0], kb1[c0]));
            float ub = fmaf(t0v, kw1[c1], fmaf(t1v, kw1[16 + c1], kb1[c1]));
            u2[cp][0]  = (_Float16)ua;              u2[cp][1]  = (_Float16)ub;
            w2p[cp][0] = (_Float16)kw2[c0 * 8 + h]; w2p[cp][1] = (_Float16)kw2[c1 * 8 + h];
        }
    }
    // sv2 staging weights for this wave's channel pair (cp == w)
    const float w0a = kw1[2 * w],     w1a = kw1[16 + 2 * w];
    const float w0b = kw1[2 * w + 1], w1b = kw1[16 + 2 * w + 1];

    // per-lane global staging sources (tile offset added per kt)
    const u16* gK = K + ((size_t)m * 1024 + lane) * 512 + h * 64 + w * 8;
    const u16* gV = Vt + (size_t)m * 524288 + (size_t)(h * 64 + lane) * 1024 + w * 8;
    const float* gT = tkp + (size_t)m * 2048 + lane * 2;

    float mrun = -1e30f, lrun = 0.f;
    f4 o[4];
    #pragma unroll
    for (int d = 0; d < 4; ++d) o[d] = (f4)0.f;

    // STAGE(kt2 -> buf nb): sv2 first (its reg-dep wait covers only its own
    // load), then K/V gl_lds which stay in flight through compute.
    auto STAGE = [&](int kt2, int nb) {
        const int k0n = kt2 * 64;
        float2 t = *(const float2*)(gT + k0n * 2);
        h2 pv;
        pv[0] = (_Float16)fmaf(t.x, w0a, t.y * w1a);
        pv[1] = (_Float16)fmaf(t.x, w0b, t.y * w1b);
        sv2[nb][w][lane] = u_of(pv);
        gl_lds16(gK + (size_t)k0n * 512, &sK[nb][w][0][0]);
        gl_lds16(gV + k0n,               &sV[nb][w][0][0]);
    };

    STAGE(0, 0);
    __syncthreads();

    int cur = 0;
    for (int kt = 0; kt < 16; ++kt) {
        if (kt < 15) STAGE(kt + 1, cur ^ 1);

        // ---- S^T = K·Q^T : s[msub] rows = keys msub*16+quad*4+r, col q=l16 ----
        f4 s[4];
        #pragma unroll
        for (int msub = 0; msub < 4; ++msub) {
            bf8 kf0 = *(const bf8*)&sK[cur][quad][msub * 16 + l16][0];
            bf8 kf1 = *(const bf8*)&sK[cur][4 + quad][msub * 16 + l16][0];
            s[msub] = __builtin_amdgcn_mfma_f32_16x16x32_bf16(kf0, qf[0], (f4)0.f, 0, 0, 0);
            s[msub] = __builtin_amdgcn_mfma_f32_16x16x32_bf16(kf1, qf[1], s[msub], 0, 0, 0);
        }
        // ---- bias: s = s*SCALE + sum_c relu(u[c]-v[c,k])*w2h[c] (packed f16) ----
        #pragma unroll
        for (int msub = 0; msub < 4; ++msub) {
            const int kb = msub * 16 + quad * 4;
            f4 b = (f4)0.f;
            #pragma unroll
            for (int cp = 0; cp < 8; ++cp) {
                uint4 vv = *(const uint4*)&sv2[cur][cp][kb];
                const h2 uc = u2[cp], wc = w2p[cp];
                const h2 z = (h2)(_Float16)0.f;
                h2 d0 = uc - h2_of(vv.x);
                h2 d1 = uc - h2_of(vv.y);
                h2 d2 = uc - h2_of(vv.z);
                h2 d3 = uc - h2_of(vv.w);
                d0 = __builtin_elementwise_max(d0, z);
                d1 = __builtin_elementwise_max(d1, z);
                d2 = __builtin_elementwise_max(d2, z);
                d3 = __builtin_elementwise_max(d3, z);
                b[0] = dot2(d0, wc, b[0]);
                b[1] = dot2(d1, wc, b[1]);
                b[2] = dot2(d2, wc, b[2]);
                b[3] = dot2(d3, wc, b[3]);
            }
            s[msub] = s[msub] * SCALE + b;
        }
        // ---- online softmax over keys (rows spread over quads) ----
        float mx = -1e30f;
        #pragma unroll
        for (int msub = 0; msub < 4; ++msub) {
            mx = fmaxf(mx, fmaxf(fmaxf(s[msub][0], s[msub][1]),
                                 fmaxf(s[msub][2], s[msub][3])));
        }
        mx = fmaxf(mx, __shfl_xor(mx, 16));
        mx = fmaxf(mx, __shfl_xor(mx, 32));
        const float mnew = fmaxf(mrun, mx);
        float ps = 0.f;
        #pragma unroll
        for (int msub = 0; msub < 4; ++msub) {
            #pragma unroll
            for (int r = 0; r < 4; ++r) {
                float p = __expf(s[msub][r] - mnew);
                s[msub][r] = p;
                ps += p;
            }
        }
        ps += __shfl_xor(ps, 16);
        ps += __shfl_xor(ps, 32);
        if (__all(mx <= mrun)) {
            lrun += ps;             // alpha == 1 exactly
        } else {
            const float alpha = __expf(mrun - mnew);
            lrun = lrun * alpha + ps;
            mrun = mnew;
            #pragma unroll
            for (int d = 0; d < 4; ++d) o[d] = o[d] * alpha;
        }
        // ---- write P (bf16) to wave-private sP[q][key] ----
        #pragma unroll
        for (int msub = 0; msub < 4; ++msub) {
            uint2 pw;
            pw.x = pk2(s[msub][0], s[msub][1]);
            pw.y = pk2(s[msub][2], s[msub][3]);
            *(uint2*)&sP[w][l16][msub * 16 + quad * 4] = pw;
        }
        // ---- O^T += Vt·P^T ----
        #pragma unroll
        for (int dsub = 0; dsub < 4; ++dsub) {
            #pragma unroll
            for (int kc2 = 0; kc2 < 2; ++kc2) {
                bf8 vf = *(const bf8*)&sV[cur][kc2 * 4 + quad][dsub * 16 + l16][0];
                bf8 pf = *(const bf8*)&sP[w][l16][kc2 * 32 + quad * 8];
                o[dsub] = __builtin_amdgcn_mfma_f32_16x16x32_bf16(vf, pf, o[dsub], 0, 0, 0);
            }
        }

        if (kt < 15) __syncthreads();   // drains prefetch; guards buffer reuse
        cur ^= 1;
    }

    // ---- epilogue: O[tok][h*64 + d] = o/l ----
    const float inv = 1.f / lrun;
    #pragma unroll
    for (int dsub = 0; dsub < 4; ++dsub) {
        uint2 pw;
        pw.x = pk2(o[dsub][0] * inv, o[dsub][1] * inv);
        pw.y = pk2(o[dsub][2] * inv, o[dsub][3] * inv);
        *(uint2*)&O[qtok * 512 + h * 64 + dsub * 16 + quad * 4] = pw;
    }
}

// ===========================================================================
extern "C" void kernel_launch(void* const* d_in, const int* in_sizes, int n_in,
                              void* d_out, int out_size, void* d_ws, size_t ws_size,
                              hipStream_t stream) {
    const float* xq    = (const float*)d_in[0];
    const float* xk    = (const float*)d_in[1];
    const float* xv    = (const float*)d_in[2];
    const float* tq    = (const float*)d_in[3];
    const float* tk    = (const float*)d_in[4];
    const float* w_q   = (const float*)d_in[5];
    const float* w_k   = (const float*)d_in[6];
    const float* w_v   = (const float*)d_in[7];
    const float* w_out = (const float*)d_in[8];
    const float* b_out = (const float*)d_in[9];
    const float* kw1   = (const float*)d_in[10];
    const float* kb1   = (const float*)d_in[11];
    const float* kw2   = (const float*)d_in[12];

    // workspace: Q | K | Vt | Aq | Ak | Av | Wq | Wk | Wv | Wo   (50 MiB)
    u16* Q  = (u16*)d_ws;
    u16* Kp = Q  + NTOK;
    u16* Vt = Kp + NTOK;
    u16* Aq = Vt + NTOK;
    u16* Ak = Aq + NTOK;
    u16* Av = Ak + NTOK;
    u16* Wq = Av + NTOK;
    u16* Wk = Wq + 262144;
    u16* Wv = Wk + 262144;
    u16* Wo = Wv + 262144;
    u16* O  = Aq;            // Aq is dead after gemm1; reuse for attn output

    // --- one-time conversions (A's -> bf16, W's -> bf16 transposed) ---
    PArgs p;
    p.xs[0] = xq;  p.xs[1] = xk;  p.xs[2] = xv;
    p.ws[0] = w_q; p.ws[1] = w_k; p.ws[2] = w_v; p.ws[3] = w_out;
    p.dstA = Aq;   p.dstW = Wq;
    prep<<<dim3(1792), 256, 0, stream>>>(p);

    // --- QKV projections (V stored transposed per batch) ---
    GArgs gq;
    gq.A[0] = Aq;  gq.A[1] = Ak;  gq.A[2] = Av;
    gq.W[0] = Wq;  gq.W[1] = Wk;  gq.W[2] = Wv;
    gq.C[0] = Q;   gq.C[1] = Kp;  gq.C[2] = Vt;
    gq.bias = nullptr;
    gq.modeT[0] = 0; gq.modeT[1] = 0; gq.modeT[2] = 1;
    gq.outf32 = 0;
    gemm_mfma<<<dim3(4, 64, 3), 256, 0, stream>>>(gq);

    // --- fused attention (128 queries/block, 8 waves) ---
    attn_mfma<<<dim3(8, 8, Mb), 512, 0, stream>>>(Q, Kp, Vt, tq, tk,
                                                  kw1, kb1, kw2, O);

    // --- output projection (f32 + bias) ---
    GArgs go;
    go.A[0] = O;   go.A[1] = O;   go.A[2] = O;
    go.W[0] = Wo;  go.W[1] = Wo;  go.W[2] = Wo;
    go.C[0] = d_out; go.C[1] = d_out; go.C[2] = d_out;
    go.bias = b_out;
    go.modeT[0] = 0; go.modeT[1] = 0; go.modeT[2] = 0;
    go.outf32 = 1;
    gemm_mfma<<<dim3(4, 64, 1), 256, 0, stream>>>(go);
}